// Round 15
// baseline (705.437 us; speedup 1.0000x reference)
//
#include <hip/hip_runtime.h>
#include <hip/hip_bf16.h>

namespace {

constexpr int T_TOK = 8192;      // B*S
constexpr int HDIM  = 1024;
constexpr int FDIM  = 3584;
constexpr int CAP_ROWS = 17408;  // T*K + 8*128 pad
constexpr int MAXMT = CAP_ROWS / 128;  // 136

typedef __bf16 bf16x8 __attribute__((ext_vector_type(8)));
typedef float  f32x4  __attribute__((ext_vector_type(4)));

#define CFENCE() asm volatile("" ::: "memory")

__device__ inline unsigned short f2bf(float f) {
  union { float f; unsigned u; } a; a.f = f;
  unsigned r = a.u + 0x7fffu + ((a.u >> 16) & 1u);   // RTN-even
  return (unsigned short)(r >> 16);
}

typedef const __attribute__((address_space(1))) void* gptr_t;
typedef __attribute__((address_space(3))) void* lptr_t;
__device__ inline void gload_lds16(const void* g, void* l) {
  __builtin_amdgcn_global_load_lds((gptr_t)g, (lptr_t)l, 16, 0, 0);
}

#define MFMA16(a, b, c) __builtin_amdgcn_mfma_f32_16x16x32_bf16(a, b, c, 0, 0, 0)

// meta layout (ints): [0..7] cnt, [8..15] cnt2, [16..23] seg off (rows),
// [24] total padded rows, [25] ntiles, [32..167] tile->expert
__global__ __launch_bounds__(256) void k_router(
    const float* __restrict__ x, const float* __restrict__ gw,
    const float* __restrict__ gw2, float* __restrict__ logits_out,
    int* __restrict__ sel, float* __restrict__ wts)
{
  int t = blockIdx.x * 4 + (threadIdx.x >> 6);
  int lane = threadIdx.x & 63;
  if (t >= T_TOK) return;
  const float* xr = x + (size_t)t * HDIM;
  float acc[10];
#pragma unroll
  for (int e = 0; e < 10; ++e) acc[e] = 0.f;
#pragma unroll
  for (int it = 0; it < 4; ++it) {
    int base = it * 256 + lane * 4;
    float4 xv = *reinterpret_cast<const float4*>(xr + base);
#pragma unroll
    for (int e = 0; e < 8; ++e) {
      float4 g = *reinterpret_cast<const float4*>(gw + e * HDIM + base);
      acc[e] += xv.x * g.x + xv.y * g.y + xv.z * g.z + xv.w * g.w;
    }
#pragma unroll
    for (int e = 0; e < 2; ++e) {
      float4 g = *reinterpret_cast<const float4*>(gw2 + e * HDIM + base);
      acc[8 + e] += xv.x * g.x + xv.y * g.y + xv.z * g.z + xv.w * g.w;
    }
  }
#pragma unroll
  for (int e = 0; e < 10; ++e) {
#pragma unroll
    for (int off = 32; off > 0; off >>= 1)
      acc[e] += __shfl_xor(acc[e], off, 64);
  }
  if (lane == 0) {
    float* lo = logits_out + (size_t)t * 10;
#pragma unroll
    for (int e = 0; e < 10; ++e) lo[e] = acc[e];
    float mx = acc[0];
#pragma unroll
    for (int e = 1; e < 10; ++e) mx = fmaxf(mx, acc[e]);
    float p[10], s = 0.f;
#pragma unroll
    for (int e = 0; e < 10; ++e) { p[e] = __expf(acc[e] - mx); s += p[e]; }
    float inv = 1.f / s;
#pragma unroll
    for (int e = 0; e < 10; ++e) p[e] *= inv;
    // top-2 over probabilities, ties -> lower index (jax.lax.top_k semantics)
    int i0 = 0;
    for (int e = 1; e < 10; ++e) if (p[e] > p[i0]) i0 = e;
    int i1 = (i0 == 0) ? 1 : 0;
    for (int e = 0; e < 10; ++e) if (e != i0 && p[e] > p[i1]) i1 = e;
    float w0 = p[i0], w1 = p[i1];
    bool r0 = i0 < 8, r1 = i1 < 8;
    float den = (r0 ? w0 : 0.f) + (r1 ? w1 : 0.f);
    if (den == 0.f) den = 1.f;
    sel[t * 2]     = i0; wts[t * 2]     = r0 ? w0 / den : 0.f;
    sel[t * 2 + 1] = i1; wts[t * 2 + 1] = r1 ? w1 / den : 0.f;
  }
}

// Fused histogram + segment setup (single block). Zero global atomics.
__global__ __launch_bounds__(256) void k_histseg(
    const int* __restrict__ sel, int* __restrict__ meta)
{
  __shared__ int part[256][8];
  __shared__ int s_tile0[9];
  int tid = threadIdx.x;
  int c[8];
#pragma unroll
  for (int e = 0; e < 8; ++e) c[e] = 0;
  for (int i = 0; i < 64; ++i) {
    int v = sel[i * 256 + tid];
#pragma unroll
    for (int e = 0; e < 8; ++e) c[e] += (v == e);
  }
#pragma unroll
  for (int e = 0; e < 8; ++e) part[tid][e] = c[e];
  __syncthreads();
  for (int s = 128; s >= 1; s >>= 1) {
    if (tid < s) {
#pragma unroll
      for (int e = 0; e < 8; ++e) part[tid][e] += part[tid + s][e];
    }
    __syncthreads();
  }
  if (tid == 0) {
    int off = 0;
    for (int e = 0; e < 8; ++e) {
      int cnt = part[0][e];
      meta[e] = cnt;
      meta[8 + e] = 0;            // scatter's running counter
      meta[16 + e] = off;
      s_tile0[e] = off >> 7;
      off += (cnt + 127) & ~127;
    }
    meta[24] = off;
    meta[25] = off >> 7;
    s_tile0[8] = off >> 7;
  }
  __syncthreads();
  int nt = s_tile0[8];
  if (tid < nt) {
    int e = 0;
    while (s_tile0[e + 1] <= tid) ++e;
    meta[32 + tid] = e;
  }
}

__global__ __launch_bounds__(256) void k_zeropad(
    const int* __restrict__ meta, unsigned short* __restrict__ xg)
{
  int e = blockIdx.x >> 7, r = blockIdx.x & 127;
  int c = meta[e];
  int pad = (c + 127) & ~127;
  if (c + r >= pad) return;
  size_t row = (size_t)meta[16 + e] + c + r;
  reinterpret_cast<ushort4*>(xg + row * HDIM)[threadIdx.x] = ushort4{0, 0, 0, 0};
}

// Block-aggregated scatter: 64 blocks x 256 pairs. LDS ranking + one
// returning global atomic per (expert, block), then cooperative row copies.
__global__ __launch_bounds__(256) void k_scatter(
    const float* __restrict__ x, const int* __restrict__ sel,
    int* __restrict__ meta, int* __restrict__ pair_row,
    unsigned short* __restrict__ xg)
{
  __shared__ int s_cnt[8];
  __shared__ int s_base[8];
  __shared__ int s_row[256];
  int tid = threadIdx.x;
  int pair0 = blockIdx.x * 256;
  if (tid < 8) s_cnt[tid] = 0;
  __syncthreads();
  int e = sel[pair0 + tid];
  int rank = -1;
  if (e < 8) rank = atomicAdd(&s_cnt[e], 1);
  __syncthreads();
  if (tid < 8) {
    int c = s_cnt[tid];
    s_base[tid] = c > 0 ? atomicAdd(&meta[8 + tid], c) : 0;
  }
  __syncthreads();
  int row = (e < 8) ? meta[16 + e] + s_base[e] + rank : -1;
  pair_row[pair0 + tid] = row;
  s_row[tid] = row;
  __syncthreads();
  int wid = tid >> 6, lane = tid & 63;
  for (int i = wid; i < 256; i += 4) {
    int r = s_row[i];
    if (r < 0) continue;
    const float* xr = x + (size_t)((pair0 + i) >> 1) * HDIM;
    unsigned short* dst = xg + (size_t)r * HDIM;
#pragma unroll
    for (int it = 0; it < 4; ++it) {
      int base = it * 256 + lane * 4;
      float4 v = *reinterpret_cast<const float4*>(xr + base);
      ushort4 o{f2bf(v.x), f2bf(v.y), f2bf(v.z), f2bf(v.w)};
      *reinterpret_cast<ushort4*>(dst + base) = o;
    }
  }
}

// One launch converting the w1/w3/w2 chunks (grid.y = matrix). Flat
// fast-path when the chunk is the whole matrix (nf == 1).
__global__ __launch_bounds__(256) void k_conv3(
    const float* __restrict__ s1, const float* __restrict__ s3,
    const float* __restrict__ s2,
    unsigned short* __restrict__ d1, unsigned short* __restrict__ d3,
    unsigned short* __restrict__ d2,
    long long total, long long rl13, long long ss13,
    long long rl2, long long ss2)
{
  long long i = ((long long)blockIdx.x * 256 + threadIdx.x) * 8;
  if (i >= total) return;
  const float* src; unsigned short* dst; long long rowlen, sstride;
  if (blockIdx.y == 0)      { src = s1; dst = d1; rowlen = rl13; sstride = ss13; }
  else if (blockIdx.y == 1) { src = s3; dst = d3; rowlen = rl13; sstride = ss13; }
  else                      { src = s2; dst = d2; rowlen = rl2;  sstride = ss2;  }
  const float* sp;
  if (rowlen == sstride) {
    sp = src + i;
  } else {
    long long r = i / rowlen, c = i - r * rowlen;
    sp = src + r * sstride + c;
  }
  float4 a = reinterpret_cast<const float4*>(sp)[0];
  float4 b = reinterpret_cast<const float4*>(sp)[1];
  ushort4* d = reinterpret_cast<ushort4*>(dst + i);
  d[0] = ushort4{f2bf(a.x), f2bf(a.y), f2bf(a.z), f2bf(a.w)};
  d[1] = ushort4{f2bf(b.x), f2bf(b.y), f2bf(b.z), f2bf(b.w)};
}

// hg = silu(xg @ w1c^T) * (xg @ w3c^T) for one F-chunk (all-bf16).
// NEW geometry: block 128M x 128N, 4 waves (2x2), per-wave 64x64 per matrix
// (m_rep=4, n_rep=4). MFMA:ds_read ratio = 32:12 = 2.67 (was 2.0) -- attacks
// the measured fragment-read/issue bound. Same proven 2-barrier loop, BK=64,
// single-buffer LDS (48 KB), XOR swizzle via pre-swizzled source (0 confl).
// b-frags loaded per-n inside the MFMA loop to cap register liveness.
__global__ __launch_bounds__(256) void k_gemm1(
    const unsigned short* __restrict__ xg,
    const unsigned short* __restrict__ wc1,
    const unsigned short* __restrict__ wc3,
    unsigned short* __restrict__ hg,
    const int* __restrict__ meta, int Fc)
{
  __shared__ unsigned short As[128 * 64];    // 16 KB
  __shared__ unsigned short B1s[128 * 64];   // 16 KB
  __shared__ unsigned short B3s[128 * 64];   // 16 KB

  int mt = blockIdx.y;
  if (mt >= meta[25]) return;
  int e = meta[32 + mt];
  int mrow0 = mt * 128;
  int fl0 = blockIdx.x * 128;  // chunk-local F col

  int tid = threadIdx.x, wid = tid >> 6, lane = tid & 63;
  int lr = lane & 15, lg = lane >> 4;
  int wm = wid >> 1, wn = wid & 1;

  f32x4 acc1[4][4], acc3[4][4];
  const f32x4 zero = {0.f, 0.f, 0.f, 0.f};
#pragma unroll
  for (int m = 0; m < 4; ++m)
#pragma unroll
    for (int n = 0; n < 4; ++n) { acc1[m][n] = zero; acc3[m][n] = zero; }

  const unsigned short* w1p = wc1 + ((size_t)e * Fc + fl0) * HDIM;
  const unsigned short* w3p = wc3 + ((size_t)e * Fc + fl0) * HDIM;

  int srow = tid >> 3;          // staging row-in-32 group
  int sc8  = tid & 7;           // staging col8 before swizzle

  for (int k0 = 0; k0 < HDIM; k0 += 64) {
#pragma unroll
    for (int i = 0; i < 4; ++i) {
      int row = i * 32 + srow;
      int c8 = sc8 ^ (row & 7);
      gload_lds16(xg + (size_t)(mrow0 + row) * HDIM + k0 + c8 * 8,
                  (char*)As + i * 4096 + wid * 1024);
      gload_lds16(w1p + (size_t)row * HDIM + k0 + c8 * 8,
                  (char*)B1s + i * 4096 + wid * 1024);
      gload_lds16(w3p + (size_t)row * HDIM + k0 + c8 * 8,
                  (char*)B3s + i * 4096 + wid * 1024);
    }
    __syncthreads();

#pragma unroll
    for (int kk = 0; kk < 2; ++kk) {
      bf16x8 a[4];
#pragma unroll
      for (int m = 0; m < 4; ++m) {
        int r = wm * 64 + m * 16 + lr;
        int off = r * 128 + ((kk * 64 + lg * 16) ^ ((r & 7) << 4));
        a[m] = *reinterpret_cast<const bf16x8*>((const char*)As + off);
      }
#pragma unroll
      for (int n = 0; n < 4; ++n) {
        int r = wn * 64 + n * 16 + lr;
        int off = r * 128 + ((kk * 64 + lg * 16) ^ ((r & 7) << 4));
        bf16x8 b1 = *reinterpret_cast<const bf16x8*>((const char*)B1s + off);
        bf16x8 b3 = *reinterpret_cast<const bf16x8*>((const char*)B3s + off);
#pragma unroll
        for (int m = 0; m < 4; ++m) {
          acc1[m][n] = MFMA16(a[m], b1, acc1[m][n]);
          acc3[m][n] = MFMA16(a[m], b3, acc3[m][n]);
        }
      }
    }
    __syncthreads();
  }

  // epilogue: silu(acc1)*acc3 -> bf16 hg (chunk-local columns)
#pragma unroll
  for (int m = 0; m < 4; ++m)
#pragma unroll
    for (int n = 0; n < 4; ++n) {
      int gcol = fl0 + wn * 64 + n * 16 + lr;
#pragma unroll
      for (int j = 0; j < 4; ++j) {
        int grow = mrow0 + wm * 64 + m * 16 + lg * 4 + j;
        float s1 = acc1[m][n][j];
        float s3 = acc3[m][n][j];
        float h = s1 / (1.f + __expf(-s1)) * s3;
        hg[(size_t)grow * Fc + gcol] = f2bf(h);
      }
    }
}

// yrows(+)= hg @ wc2^T for one F-chunk. wc2 layout: [E][H][Fc] bf16.
// R6-proven frame: 128x128 tile, BK=64, dbuf + counted-vmcnt(8), fp32 out.
__global__ __launch_bounds__(256) void k_gemm2(
    const unsigned short* __restrict__ hg,
    const unsigned short* __restrict__ wc2,
    float* __restrict__ yrows, const int* __restrict__ meta,
    int Fc, int first)
{
  __shared__ __attribute__((aligned(128))) char lds[65536];
  // per buffer (stride 32768): A @0 (16K), B @16384 (16K)

  int mt = blockIdx.y;
  if (mt >= meta[25]) return;
  int e = meta[32 + mt];
  int mrow0 = mt * 128;
  int hcol0 = blockIdx.x * 128;

  int tid = threadIdx.x, wid = tid >> 6, lane = tid & 63;
  int lr = lane & 15, lg = lane >> 4;
  int wm = wid >> 1, wn = wid & 1;

  f32x4 acc[4][4];
  const f32x4 zero = {0.f, 0.f, 0.f, 0.f};
#pragma unroll
  for (int m = 0; m < 4; ++m)
#pragma unroll
    for (int n = 0; n < 4; ++n) acc[m][n] = zero;

  const unsigned short* w2p = wc2 + ((size_t)e * HDIM + hcol0) * Fc;

  int srow = tid >> 3;
  int c8 = (tid & 7) ^ (srow & 7);

  const unsigned short* pa[4];
  const unsigned short* pb[4];
#pragma unroll
  for (int i = 0; i < 4; ++i) {
    pa[i] = hg + (size_t)(mrow0 + i * 32 + srow) * Fc + c8 * 8;
    pb[i] = w2p + (size_t)(i * 32 + srow) * Fc + c8 * 8;
  }

  auto STAGE = [&](int buf) {
    char* base = lds + buf * 32768;
#pragma unroll
    for (int i = 0; i < 4; ++i) {
      gload_lds16(pa[i], base + i * 4096 + wid * 1024);
      pa[i] += 64;
      gload_lds16(pb[i], base + 16384 + i * 4096 + wid * 1024);
      pb[i] += 64;
    }
  };

  auto COMPUTE = [&](int buf) {
    const char* base = lds + buf * 32768;
#pragma unroll
    for (int kk = 0; kk < 2; ++kk) {
      bf16x8 a[4], b[4];
#pragma unroll
      for (int m = 0; m < 4; ++m) {
        int r = wm * 64 + m * 16 + lr;
        int off = r * 128 + ((kk * 64 + lg * 16) ^ ((r & 7) << 4));
        a[m] = *reinterpret_cast<const bf16x8*>(base + off);
      }
#pragma unroll
      for (int n = 0; n < 4; ++n) {
        int r = wn * 64 + n * 16 + lr;
        int off = r * 128 + ((kk * 64 + lg * 16) ^ ((r & 7) << 4));
        b[n] = *reinterpret_cast<const bf16x8*>(base + 16384 + off);
      }
#pragma unroll
      for (int m = 0; m < 4; ++m)
#pragma unroll
        for (int n = 0; n < 4; ++n)
          acc[m][n] = MFMA16(a[m], b[n], acc[m][n]);
    }
  };

  int NT = Fc / 64;
  int cur = 0;
  STAGE(0);
#pragma unroll 1
  for (int t = 0; t < NT - 1; ++t) {
    STAGE(cur ^ 1);
    asm volatile("s_waitcnt vmcnt(8)" ::: "memory");
    __builtin_amdgcn_s_barrier();
    CFENCE();
    COMPUTE(cur);
    CFENCE();
    __builtin_amdgcn_s_barrier();
    cur ^= 1;
  }
  asm volatile("s_waitcnt vmcnt(0)" ::: "memory");
  __builtin_amdgcn_s_barrier();
  CFENCE();
  COMPUTE(cur);

#pragma unroll
  for (int m = 0; m < 4; ++m)
#pragma unroll
    for (int n = 0; n < 4; ++n) {
      int gcol = hcol0 + wn * 64 + n * 16 + lr;
#pragma unroll
      for (int j = 0; j < 4; ++j) {
        int grow = mrow0 + wm * 64 + m * 16 + lg * 4 + j;
        float* yp = yrows + (size_t)grow * HDIM + gcol;
        float v = acc[m][n][j];
        if (first) *yp = v; else *yp += v;
      }
    }
}

__global__ __launch_bounds__(256) void k_combine(
    const float* __restrict__ yrows, const int* __restrict__ pair_row,
    const float* __restrict__ wts, float* __restrict__ out)
{
  int t = blockIdx.x * 4 + (threadIdx.x >> 6);
  int lane = threadIdx.x & 63;
  if (t >= T_TOK) return;
  int r0 = pair_row[t * 2], r1 = pair_row[t * 2 + 1];
  float w0 = (r0 >= 0) ? wts[t * 2] : 0.f;
  float w1 = (r1 >= 0) ? wts[t * 2 + 1] : 0.f;
  const float* y0 = yrows + (size_t)(r0 >= 0 ? r0 : 0) * HDIM;
  const float* y1 = yrows + (size_t)(r1 >= 0 ? r1 : 0) * HDIM;
  float* op = out + (size_t)t * HDIM;
#pragma unroll
  for (int it = 0; it < 4; ++it) {
    int base = it * 256 + lane * 4;
    float4 a = *reinterpret_cast<const float4*>(y0 + base);
    float4 b = *reinterpret_cast<const float4*>(y1 + base);
    float4 r{w0 * a.x + w1 * b.x, w0 * a.y + w1 * b.y,
             w0 * a.z + w1 * b.z, w0 * a.w + w1 * b.w};
    *reinterpret_cast<float4*>(op + base) = r;
  }
}

}  // namespace

extern "C" void kernel_launch(void* const* d_in, const int* in_sizes, int n_in,
                              void* d_out, int out_size, void* d_ws, size_t ws_size,
                              hipStream_t stream)
{
  const float* x   = (const float*)d_in[0];
  const float* gw  = (const float*)d_in[1];
  const float* gw2 = (const float*)d_in[2];
  const float* w1  = (const float*)d_in[3];
  const float* w2  = (const float*)d_in[4];
  const float* w3  = (const float*)d_in[5];
  float* out = (float*)d_out;
  float* logits_out = out + (size_t)T_TOK * HDIM;

  char* p = (char*)d_ws;
  int* meta = (int*)p;            p += 1024;
  int* sel = (int*)p;             p += T_TOK * 2 * sizeof(int);
  float* wts = (float*)p;         p += T_TOK * 2 * sizeof(float);
  int* pair_row = (int*)p;        p += T_TOK * 2 * sizeof(int);
  unsigned short* xg = (unsigned short*)p;  p += (size_t)CAP_ROWS * HDIM * 2;
  float* yrows = (float*)p;                 p += (size_t)CAP_ROWS * HDIM * 4;
  size_t fixed = (size_t)(p - (char*)d_ws);

  // per-chunk buffers: wc1 = wc3 = wc2 = 16384*Fc bytes each; hg = 34816*Fc.
  // pick the largest Fc (fewest chunks) that fits the workspace.
  int nf = 28;
  const int opts[6] = {1, 2, 4, 7, 14, 28};
  for (int i = 0; i < 6; ++i) {
    size_t Fc_i = FDIM / opts[i];
    size_t need = fixed + 3 * 16384 * Fc_i + (size_t)CAP_ROWS * Fc_i * 2;
    if (need <= ws_size) { nf = opts[i]; break; }
  }
  int Fc = FDIM / nf;

  unsigned short* wc1 = (unsigned short*)p;  p += (size_t)16384 * Fc;
  unsigned short* wc3 = (unsigned short*)p;  p += (size_t)16384 * Fc;
  unsigned short* wc2 = (unsigned short*)p;  p += (size_t)16384 * Fc;
  unsigned short* hg  = (unsigned short*)p;

  k_router<<<T_TOK / 4, 256, 0, stream>>>(x, gw, gw2, logits_out, sel, wts);
  k_histseg<<<1, 256, 0, stream>>>(sel, meta);
  k_zeropad<<<1024, 256, 0, stream>>>(meta, xg);
  k_scatter<<<T_TOK * 2 / 256, 256, 0, stream>>>(x, sel, meta, pair_row, xg);

  long long total = 8LL * Fc * HDIM;               // elems per matrix per chunk
  int ncb = (int)(total / 8 / 256);                // exact
  for (int c = 0; c < nf; ++c) {
    long long c0 = (long long)c * Fc;
    k_conv3<<<dim3(ncb, 3), 256, 0, stream>>>(
        w1 + c0 * HDIM, w3 + c0 * HDIM, w2 + c0, wc1, wc3, wc2,
        total, (long long)Fc * HDIM, (long long)FDIM * HDIM,
        (long long)Fc, (long long)FDIM);

    k_gemm1<<<dim3(Fc / 128, MAXMT), 256, 0, stream>>>(xg, wc1, wc3, hg, meta, Fc);
    k_gemm2<<<dim3(HDIM / 128, MAXMT), 256, 0, stream>>>(hg, wc2, yrows, meta, Fc, c == 0 ? 1 : 0);
  }
  k_combine<<<T_TOK / 4, 256, 0, stream>>>(yrows, pair_row, wts, out);
}

// Round 16
// 525.689 us; speedup vs baseline: 1.3419x; 1.3419x over previous
//
#include <hip/hip_runtime.h>
#include <hip/hip_bf16.h>

namespace {

constexpr int T_TOK = 8192;      // B*S
constexpr int HDIM  = 1024;
constexpr int FDIM  = 3584;
constexpr int CAP_ROWS = 17408;  // T*K + 8*128 pad
constexpr int MAXMT = CAP_ROWS / 128;  // 136

typedef __bf16 bf16x8 __attribute__((ext_vector_type(8)));
typedef float  f32x4  __attribute__((ext_vector_type(4)));

#define CFENCE() asm volatile("" ::: "memory")

__device__ inline unsigned short f2bf(float f) {
  union { float f; unsigned u; } a; a.f = f;
  unsigned r = a.u + 0x7fffu + ((a.u >> 16) & 1u);   // RTN-even
  return (unsigned short)(r >> 16);
}

typedef const __attribute__((address_space(1))) void* gptr_t;
typedef __attribute__((address_space(3))) void* lptr_t;
__device__ inline void gload_lds16(const void* g, void* l) {
  __builtin_amdgcn_global_load_lds((gptr_t)g, (lptr_t)l, 16, 0, 0);
}

#define MFMA16(a, b, c) __builtin_amdgcn_mfma_f32_16x16x32_bf16(a, b, c, 0, 0, 0)

// meta layout (ints): [0..7] cnt, [8..15] cnt2, [16..23] seg off (rows),
// [24] total padded rows, [25] ntiles, [32..167] tile->expert
__global__ __launch_bounds__(256) void k_router(
    const float* __restrict__ x, const float* __restrict__ gw,
    const float* __restrict__ gw2, float* __restrict__ logits_out,
    int* __restrict__ sel, float* __restrict__ wts)
{
  int t = blockIdx.x * 4 + (threadIdx.x >> 6);
  int lane = threadIdx.x & 63;
  if (t >= T_TOK) return;
  const float* xr = x + (size_t)t * HDIM;
  float acc[10];
#pragma unroll
  for (int e = 0; e < 10; ++e) acc[e] = 0.f;
#pragma unroll
  for (int it = 0; it < 4; ++it) {
    int base = it * 256 + lane * 4;
    float4 xv = *reinterpret_cast<const float4*>(xr + base);
#pragma unroll
    for (int e = 0; e < 8; ++e) {
      float4 g = *reinterpret_cast<const float4*>(gw + e * HDIM + base);
      acc[e] += xv.x * g.x + xv.y * g.y + xv.z * g.z + xv.w * g.w;
    }
#pragma unroll
    for (int e = 0; e < 2; ++e) {
      float4 g = *reinterpret_cast<const float4*>(gw2 + e * HDIM + base);
      acc[8 + e] += xv.x * g.x + xv.y * g.y + xv.z * g.z + xv.w * g.w;
    }
  }
#pragma unroll
  for (int e = 0; e < 10; ++e) {
#pragma unroll
    for (int off = 32; off > 0; off >>= 1)
      acc[e] += __shfl_xor(acc[e], off, 64);
  }
  if (lane == 0) {
    float* lo = logits_out + (size_t)t * 10;
#pragma unroll
    for (int e = 0; e < 10; ++e) lo[e] = acc[e];
    float mx = acc[0];
#pragma unroll
    for (int e = 1; e < 10; ++e) mx = fmaxf(mx, acc[e]);
    float p[10], s = 0.f;
#pragma unroll
    for (int e = 0; e < 10; ++e) { p[e] = __expf(acc[e] - mx); s += p[e]; }
    float inv = 1.f / s;
#pragma unroll
    for (int e = 0; e < 10; ++e) p[e] *= inv;
    // top-2 over probabilities, ties -> lower index (jax.lax.top_k semantics)
    int i0 = 0;
    for (int e = 1; e < 10; ++e) if (p[e] > p[i0]) i0 = e;
    int i1 = (i0 == 0) ? 1 : 0;
    for (int e = 0; e < 10; ++e) if (e != i0 && p[e] > p[i1]) i1 = e;
    float w0 = p[i0], w1 = p[i1];
    bool r0 = i0 < 8, r1 = i1 < 8;
    float den = (r0 ? w0 : 0.f) + (r1 ? w1 : 0.f);
    if (den == 0.f) den = 1.f;
    sel[t * 2]     = i0; wts[t * 2]     = r0 ? w0 / den : 0.f;
    sel[t * 2 + 1] = i1; wts[t * 2 + 1] = r1 ? w1 / den : 0.f;
  }
}

// Fused histogram + segment setup (single block). Zero global atomics.
__global__ __launch_bounds__(256) void k_histseg(
    const int* __restrict__ sel, int* __restrict__ meta)
{
  __shared__ int part[256][8];
  __shared__ int s_tile0[9];
  int tid = threadIdx.x;
  int c[8];
#pragma unroll
  for (int e = 0; e < 8; ++e) c[e] = 0;
  for (int i = 0; i < 64; ++i) {
    int v = sel[i * 256 + tid];
#pragma unroll
    for (int e = 0; e < 8; ++e) c[e] += (v == e);
  }
#pragma unroll
  for (int e = 0; e < 8; ++e) part[tid][e] = c[e];
  __syncthreads();
  for (int s = 128; s >= 1; s >>= 1) {
    if (tid < s) {
#pragma unroll
      for (int e = 0; e < 8; ++e) part[tid][e] += part[tid + s][e];
    }
    __syncthreads();
  }
  if (tid == 0) {
    int off = 0;
    for (int e = 0; e < 8; ++e) {
      int cnt = part[0][e];
      meta[e] = cnt;
      meta[8 + e] = 0;            // scatter's running counter
      meta[16 + e] = off;
      s_tile0[e] = off >> 7;
      off += (cnt + 127) & ~127;
    }
    meta[24] = off;
    meta[25] = off >> 7;
    s_tile0[8] = off >> 7;
  }
  __syncthreads();
  int nt = s_tile0[8];
  if (tid < nt) {
    int e = 0;
    while (s_tile0[e + 1] <= tid) ++e;
    meta[32 + tid] = e;
  }
}

__global__ __launch_bounds__(256) void k_zeropad(
    const int* __restrict__ meta, unsigned short* __restrict__ xg)
{
  int e = blockIdx.x >> 7, r = blockIdx.x & 127;
  int c = meta[e];
  int pad = (c + 127) & ~127;
  if (c + r >= pad) return;
  size_t row = (size_t)meta[16 + e] + c + r;
  reinterpret_cast<ushort4*>(xg + row * HDIM)[threadIdx.x] = ushort4{0, 0, 0, 0};
}

// Block-aggregated scatter: 64 blocks x 256 pairs. LDS ranking + one
// returning global atomic per (expert, block), then cooperative row copies.
__global__ __launch_bounds__(256) void k_scatter(
    const float* __restrict__ x, const int* __restrict__ sel,
    int* __restrict__ meta, int* __restrict__ pair_row,
    unsigned short* __restrict__ xg)
{
  __shared__ int s_cnt[8];
  __shared__ int s_base[8];
  __shared__ int s_row[256];
  int tid = threadIdx.x;
  int pair0 = blockIdx.x * 256;
  if (tid < 8) s_cnt[tid] = 0;
  __syncthreads();
  int e = sel[pair0 + tid];
  int rank = -1;
  if (e < 8) rank = atomicAdd(&s_cnt[e], 1);
  __syncthreads();
  if (tid < 8) {
    int c = s_cnt[tid];
    s_base[tid] = c > 0 ? atomicAdd(&meta[8 + tid], c) : 0;
  }
  __syncthreads();
  int row = (e < 8) ? meta[16 + e] + s_base[e] + rank : -1;
  pair_row[pair0 + tid] = row;
  s_row[tid] = row;
  __syncthreads();
  int wid = tid >> 6, lane = tid & 63;
  for (int i = wid; i < 256; i += 4) {
    int r = s_row[i];
    if (r < 0) continue;
    const float* xr = x + (size_t)((pair0 + i) >> 1) * HDIM;
    unsigned short* dst = xg + (size_t)r * HDIM;
#pragma unroll
    for (int it = 0; it < 4; ++it) {
      int base = it * 256 + lane * 4;
      float4 v = *reinterpret_cast<const float4*>(xr + base);
      ushort4 o{f2bf(v.x), f2bf(v.y), f2bf(v.z), f2bf(v.w)};
      *reinterpret_cast<ushort4*>(dst + base) = o;
    }
  }
}

// One launch converting the w1/w3/w2 chunks (grid.y = matrix). Flat
// fast-path when the chunk is the whole matrix (nf == 1).
__global__ __launch_bounds__(256) void k_conv3(
    const float* __restrict__ s1, const float* __restrict__ s3,
    const float* __restrict__ s2,
    unsigned short* __restrict__ d1, unsigned short* __restrict__ d3,
    unsigned short* __restrict__ d2,
    long long total, long long rl13, long long ss13,
    long long rl2, long long ss2)
{
  long long i = ((long long)blockIdx.x * 256 + threadIdx.x) * 8;
  if (i >= total) return;
  const float* src; unsigned short* dst; long long rowlen, sstride;
  if (blockIdx.y == 0)      { src = s1; dst = d1; rowlen = rl13; sstride = ss13; }
  else if (blockIdx.y == 1) { src = s3; dst = d3; rowlen = rl13; sstride = ss13; }
  else                      { src = s2; dst = d2; rowlen = rl2;  sstride = ss2;  }
  const float* sp;
  if (rowlen == sstride) {
    sp = src + i;
  } else {
    long long r = i / rowlen, c = i - r * rowlen;
    sp = src + r * sstride + c;
  }
  float4 a = reinterpret_cast<const float4*>(sp)[0];
  float4 b = reinterpret_cast<const float4*>(sp)[1];
  ushort4* d = reinterpret_cast<ushort4*>(dst + i);
  d[0] = ushort4{f2bf(a.x), f2bf(a.y), f2bf(a.z), f2bf(a.w)};
  d[1] = ushort4{f2bf(b.x), f2bf(b.y), f2bf(b.z), f2bf(b.w)};
}

// hg = silu(xg @ w1c^T) * (xg @ w3c^T) for one F-chunk (all-bf16).
// R5-proven frame (239 us, verified R14): 128M x 64N block, 4 waves (2x2),
// BK=64, single-buffer 32KB LDS, 2-barrier loop, 16x16x32 MFMA, XOR swizzle
// via pre-swizzled source + XOR'd ds_read (0 bank conflicts measured).
__global__ __launch_bounds__(256) void k_gemm1(
    const unsigned short* __restrict__ xg,
    const unsigned short* __restrict__ wc1,
    const unsigned short* __restrict__ wc3,
    unsigned short* __restrict__ hg,
    const int* __restrict__ meta, int Fc)
{
  __shared__ unsigned short As[128 * 64];   // 16 KB
  __shared__ unsigned short B1s[64 * 64];   //  8 KB
  __shared__ unsigned short B3s[64 * 64];   //  8 KB

  int mt = blockIdx.y;
  if (mt >= meta[25]) return;
  int e = meta[32 + mt];
  int mrow0 = mt * 128;
  int fl0 = blockIdx.x * 64;  // chunk-local F col

  int tid = threadIdx.x, wid = tid >> 6, lane = tid & 63;
  int lr = lane & 15, lg = lane >> 4;
  int wm = wid >> 1, wn = wid & 1;

  f32x4 acc1[4][2], acc3[4][2];
  const f32x4 zero = {0.f, 0.f, 0.f, 0.f};
#pragma unroll
  for (int m = 0; m < 4; ++m)
#pragma unroll
    for (int n = 0; n < 2; ++n) { acc1[m][n] = zero; acc3[m][n] = zero; }

  const unsigned short* w1p = wc1 + ((size_t)e * Fc + fl0) * HDIM;
  const unsigned short* w3p = wc3 + ((size_t)e * Fc + fl0) * HDIM;

  int srow = tid >> 3;          // staging row-in-32 group
  int sc8  = tid & 7;           // staging col8 before swizzle

  for (int k0 = 0; k0 < HDIM; k0 += 64) {
#pragma unroll
    for (int i = 0; i < 4; ++i) {
      int row = i * 32 + srow;
      int c8 = sc8 ^ (row & 7);
      gload_lds16(xg + (size_t)(mrow0 + row) * HDIM + k0 + c8 * 8,
                  (char*)As + i * 4096 + wid * 1024);
    }
#pragma unroll
    for (int i = 0; i < 2; ++i) {
      int row = i * 32 + srow;
      int c8 = sc8 ^ (row & 7);
      gload_lds16(w1p + (size_t)row * HDIM + k0 + c8 * 8,
                  (char*)B1s + i * 4096 + wid * 1024);
      gload_lds16(w3p + (size_t)row * HDIM + k0 + c8 * 8,
                  (char*)B3s + i * 4096 + wid * 1024);
    }
    __syncthreads();

#pragma unroll
    for (int kk = 0; kk < 2; ++kk) {
      bf16x8 a[4], b1[2], b3[2];
#pragma unroll
      for (int m = 0; m < 4; ++m) {
        int r = wm * 64 + m * 16 + lr;
        int off = r * 128 + ((kk * 64 + lg * 16) ^ ((r & 7) << 4));
        a[m] = *reinterpret_cast<const bf16x8*>((const char*)As + off);
      }
#pragma unroll
      for (int n = 0; n < 2; ++n) {
        int r = wn * 32 + n * 16 + lr;
        int off = r * 128 + ((kk * 64 + lg * 16) ^ ((r & 7) << 4));
        b1[n] = *reinterpret_cast<const bf16x8*>((const char*)B1s + off);
        b3[n] = *reinterpret_cast<const bf16x8*>((const char*)B3s + off);
      }
#pragma unroll
      for (int m = 0; m < 4; ++m)
#pragma unroll
        for (int n = 0; n < 2; ++n) {
          acc1[m][n] = MFMA16(a[m], b1[n], acc1[m][n]);
          acc3[m][n] = MFMA16(a[m], b3[n], acc3[m][n]);
        }
    }
    __syncthreads();
  }

  // epilogue: silu(acc1)*acc3 -> bf16 hg (chunk-local columns)
#pragma unroll
  for (int m = 0; m < 4; ++m)
#pragma unroll
    for (int n = 0; n < 2; ++n) {
      int gcol = fl0 + wn * 32 + n * 16 + lr;
#pragma unroll
      for (int j = 0; j < 4; ++j) {
        int grow = mrow0 + wm * 64 + m * 16 + lg * 4 + j;
        float s1 = acc1[m][n][j];
        float s3 = acc3[m][n][j];
        float h = s1 / (1.f + __expf(-s1)) * s3;
        hg[(size_t)grow * Fc + gcol] = f2bf(h);
      }
    }
}

// yrows(+)= hg @ wc2^T for one F-chunk. wc2 layout: [E][H][Fc] bf16.
// R6-proven frame: 128x128 tile, BK=64, dbuf + counted-vmcnt(8), fp32 out.
__global__ __launch_bounds__(256) void k_gemm2(
    const unsigned short* __restrict__ hg,
    const unsigned short* __restrict__ wc2,
    float* __restrict__ yrows, const int* __restrict__ meta,
    int Fc, int first)
{
  __shared__ __attribute__((aligned(128))) char lds[65536];
  // per buffer (stride 32768): A @0 (16K), B @16384 (16K)

  int mt = blockIdx.y;
  if (mt >= meta[25]) return;
  int e = meta[32 + mt];
  int mrow0 = mt * 128;
  int hcol0 = blockIdx.x * 128;

  int tid = threadIdx.x, wid = tid >> 6, lane = tid & 63;
  int lr = lane & 15, lg = lane >> 4;
  int wm = wid >> 1, wn = wid & 1;

  f32x4 acc[4][4];
  const f32x4 zero = {0.f, 0.f, 0.f, 0.f};
#pragma unroll
  for (int m = 0; m < 4; ++m)
#pragma unroll
    for (int n = 0; n < 4; ++n) acc[m][n] = zero;

  const unsigned short* w2p = wc2 + ((size_t)e * HDIM + hcol0) * Fc;

  int srow = tid >> 3;
  int c8 = (tid & 7) ^ (srow & 7);

  const unsigned short* pa[4];
  const unsigned short* pb[4];
#pragma unroll
  for (int i = 0; i < 4; ++i) {
    pa[i] = hg + (size_t)(mrow0 + i * 32 + srow) * Fc + c8 * 8;
    pb[i] = w2p + (size_t)(i * 32 + srow) * Fc + c8 * 8;
  }

  auto STAGE = [&](int buf) {
    char* base = lds + buf * 32768;
#pragma unroll
    for (int i = 0; i < 4; ++i) {
      gload_lds16(pa[i], base + i * 4096 + wid * 1024);
      pa[i] += 64;
      gload_lds16(pb[i], base + 16384 + i * 4096 + wid * 1024);
      pb[i] += 64;
    }
  };

  auto COMPUTE = [&](int buf) {
    const char* base = lds + buf * 32768;
#pragma unroll
    for (int kk = 0; kk < 2; ++kk) {
      bf16x8 a[4], b[4];
#pragma unroll
      for (int m = 0; m < 4; ++m) {
        int r = wm * 64 + m * 16 + lr;
        int off = r * 128 + ((kk * 64 + lg * 16) ^ ((r & 7) << 4));
        a[m] = *reinterpret_cast<const bf16x8*>(base + off);
      }
#pragma unroll
      for (int n = 0; n < 4; ++n) {
        int r = wn * 64 + n * 16 + lr;
        int off = r * 128 + ((kk * 64 + lg * 16) ^ ((r & 7) << 4));
        b[n] = *reinterpret_cast<const bf16x8*>(base + 16384 + off);
      }
#pragma unroll
      for (int m = 0; m < 4; ++m)
#pragma unroll
        for (int n = 0; n < 4; ++n)
          acc[m][n] = MFMA16(a[m], b[n], acc[m][n]);
    }
  };

  int NT = Fc / 64;
  int cur = 0;
  STAGE(0);
#pragma unroll 1
  for (int t = 0; t < NT - 1; ++t) {
    STAGE(cur ^ 1);
    asm volatile("s_waitcnt vmcnt(8)" ::: "memory");
    __builtin_amdgcn_s_barrier();
    CFENCE();
    COMPUTE(cur);
    CFENCE();
    __builtin_amdgcn_s_barrier();
    cur ^= 1;
  }
  asm volatile("s_waitcnt vmcnt(0)" ::: "memory");
  __builtin_amdgcn_s_barrier();
  CFENCE();
  COMPUTE(cur);

#pragma unroll
  for (int m = 0; m < 4; ++m)
#pragma unroll
    for (int n = 0; n < 4; ++n) {
      int gcol = hcol0 + wn * 64 + n * 16 + lr;
#pragma unroll
      for (int j = 0; j < 4; ++j) {
        int grow = mrow0 + wm * 64 + m * 16 + lg * 4 + j;
        float* yp = yrows + (size_t)grow * HDIM + gcol;
        float v = acc[m][n][j];
        if (first) *yp = v; else *yp += v;
      }
    }
}

__global__ __launch_bounds__(256) void k_combine(
    const float* __restrict__ yrows, const int* __restrict__ pair_row,
    const float* __restrict__ wts, float* __restrict__ out)
{
  int t = blockIdx.x * 4 + (threadIdx.x >> 6);
  int lane = threadIdx.x & 63;
  if (t >= T_TOK) return;
  int r0 = pair_row[t * 2], r1 = pair_row[t * 2 + 1];
  float w0 = (r0 >= 0) ? wts[t * 2] : 0.f;
  float w1 = (r1 >= 0) ? wts[t * 2 + 1] : 0.f;
  const float* y0 = yrows + (size_t)(r0 >= 0 ? r0 : 0) * HDIM;
  const float* y1 = yrows + (size_t)(r1 >= 0 ? r1 : 0) * HDIM;
  float* op = out + (size_t)t * HDIM;
#pragma unroll
  for (int it = 0; it < 4; ++it) {
    int base = it * 256 + lane * 4;
    float4 a = *reinterpret_cast<const float4*>(y0 + base);
    float4 b = *reinterpret_cast<const float4*>(y1 + base);
    float4 r{w0 * a.x + w1 * b.x, w0 * a.y + w1 * b.y,
             w0 * a.z + w1 * b.z, w0 * a.w + w1 * b.w};
    *reinterpret_cast<float4*>(op + base) = r;
  }
}

}  // namespace

extern "C" void kernel_launch(void* const* d_in, const int* in_sizes, int n_in,
                              void* d_out, int out_size, void* d_ws, size_t ws_size,
                              hipStream_t stream)
{
  const float* x   = (const float*)d_in[0];
  const float* gw  = (const float*)d_in[1];
  const float* gw2 = (const float*)d_in[2];
  const float* w1  = (const float*)d_in[3];
  const float* w2  = (const float*)d_in[4];
  const float* w3  = (const float*)d_in[5];
  float* out = (float*)d_out;
  float* logits_out = out + (size_t)T_TOK * HDIM;

  char* p = (char*)d_ws;
  int* meta = (int*)p;            p += 1024;
  int* sel = (int*)p;             p += T_TOK * 2 * sizeof(int);
  float* wts = (float*)p;         p += T_TOK * 2 * sizeof(float);
  int* pair_row = (int*)p;        p += T_TOK * 2 * sizeof(int);
  unsigned short* xg = (unsigned short*)p;  p += (size_t)CAP_ROWS * HDIM * 2;
  float* yrows = (float*)p;                 p += (size_t)CAP_ROWS * HDIM * 4;
  size_t fixed = (size_t)(p - (char*)d_ws);

  // per-chunk buffers: wc1 = wc3 = wc2 = 16384*Fc bytes each; hg = 34816*Fc.
  // pick the largest Fc (fewest chunks) that fits the workspace.
  int nf = 28;
  const int opts[6] = {1, 2, 4, 7, 14, 28};
  for (int i = 0; i < 6; ++i) {
    size_t Fc_i = FDIM / opts[i];
    size_t need = fixed + 3 * 16384 * Fc_i + (size_t)CAP_ROWS * Fc_i * 2;
    if (need <= ws_size) { nf = opts[i]; break; }
  }
  int Fc = FDIM / nf;

  unsigned short* wc1 = (unsigned short*)p;  p += (size_t)16384 * Fc;
  unsigned short* wc3 = (unsigned short*)p;  p += (size_t)16384 * Fc;
  unsigned short* wc2 = (unsigned short*)p;  p += (size_t)16384 * Fc;
  unsigned short* hg  = (unsigned short*)p;

  k_router<<<T_TOK / 4, 256, 0, stream>>>(x, gw, gw2, logits_out, sel, wts);
  k_histseg<<<1, 256, 0, stream>>>(sel, meta);
  k_zeropad<<<1024, 256, 0, stream>>>(meta, xg);
  k_scatter<<<T_TOK * 2 / 256, 256, 0, stream>>>(x, sel, meta, pair_row, xg);

  long long total = 8LL * Fc * HDIM;               // elems per matrix per chunk
  int ncb = (int)(total / 8 / 256);                // exact
  for (int c = 0; c < nf; ++c) {
    long long c0 = (long long)c * Fc;
    k_conv3<<<dim3(ncb, 3), 256, 0, stream>>>(
        w1 + c0 * HDIM, w3 + c0 * HDIM, w2 + c0, wc1, wc3, wc2,
        total, (long long)Fc * HDIM, (long long)FDIM * HDIM,
        (long long)Fc, (long long)FDIM);

    k_gemm1<<<dim3(Fc / 64, MAXMT), 256, 0, stream>>>(xg, wc1, wc3, hg, meta, Fc);
    k_gemm2<<<dim3(HDIM / 128, MAXMT), 256, 0, stream>>>(hg, wc2, yrows, meta, Fc, c == 0 ? 1 : 0);
  }
  k_combine<<<T_TOK / 4, 256, 0, stream>>>(yrows, pair_row, wts, out);
}